// Round 2
// baseline (4095.387 us; speedup 1.0000x reference)
//
#include <hip/hip_runtime.h>
#include <math.h>

#define HH 180
#define WW 240
#define T_AGGC 3
#define NBC 4
#define BBC (NBC * T_AGGC)          // 12
#define M_EVC 32
#define ROWS (BBC * 2 * HH * WW)    // 1,036,800
#define MLPH 20
#define RNNH 20
#define LRELU_SLOPE 0.1f

__device__ __forceinline__ float lrelu(float x) { return x > 0.0f ? x : LRELU_SLOPE * x; }
__device__ __forceinline__ float sigm(float x)  { return 1.0f / (1.0f + __expf(-x)); }
__device__ __forceinline__ float ftanh(float x) { return 1.0f - 2.0f / (__expf(2.0f * x) + 1.0f); }

// ---------------- Kernel 1: per-event MLP + scatter ----------------
__global__ __launch_bounds__(256) void ev_mlp_scatter(
    const float* __restrict__ ev, int n,
    const float* __restrict__ W1, const float* __restrict__ b1,
    const float* __restrict__ W2, const float* __restrict__ b2,
    const float* __restrict__ W3, const float* __restrict__ b3,
    float* __restrict__ vox, unsigned int* __restrict__ mask,
    float* __restrict__ rsum)
{
    __shared__ __align__(16) float sW2[MLPH * MLPH];
    __shared__ float sW1[MLPH], sb1[MLPH], sb2[MLPH], sW3[MLPH];
    __shared__ float sb3;
    int tid = threadIdx.x;
    for (int i = tid; i < MLPH * MLPH; i += blockDim.x) sW2[i] = W2[i];
    if (tid < MLPH) { sW1[tid] = W1[tid]; sb1[tid] = b1[tid]; sb2[tid] = b2[tid]; sW3[tid] = W3[tid]; }
    if (tid == 0) sb3 = b3[0];
    __syncthreads();

    int i = blockIdx.x * blockDim.x + tid;
    if (i >= n) return;
    const float* e = ev + (size_t)i * 7;
    float t = e[3];

    float h1[MLPH];
#pragma unroll
    for (int k = 0; k < MLPH; k++) h1[k] = lrelu(fmaf(t, sW1[k], sb1[k]));

    float val = sb3;
#pragma unroll
    for (int j = 0; j < MLPH; j++) {
        float a = sb2[j];
        const float4* wr = (const float4*)&sW2[j * MLPH];
#pragma unroll
        for (int k4 = 0; k4 < MLPH / 4; k4++) {
            float4 w = wr[k4];
            a = fmaf(h1[k4 * 4 + 0], w.x, a);
            a = fmaf(h1[k4 * 4 + 1], w.y, a);
            a = fmaf(h1[k4 * 4 + 2], w.z, a);
            a = fmaf(h1[k4 * 4 + 3], w.w, a);
        }
        val = fmaf(lrelu(a), sW3[j], val);
    }

    int xi = (int)e[0], yi = (int)e[1], pi = (int)e[2];
    int ipi = (int)e[4], ti = (int)e[5], bi = (int)e[6];
    int row = xi + WW * yi + WW * HH * pi + 2 * WW * HH * (bi * T_AGGC + ti);
    int pos = ipi - 1;
    vox[(size_t)row * M_EVC + pos] = val;
    if (val != 0.0f) {                       // matches (vox != 0) semantics
        atomicOr(&mask[row], 1u << pos);
        atomicAdd(&rsum[row], val);
    }
}

// ---------------- Kernel 2: per-row LSTM (gate-accumulator layout) ----------------
// gates g[0:20]=i, g[20:40]=f, g[40:60]=g, g[60:80]=o
__global__ __launch_bounds__(256, 2) void row_lstm(
    const unsigned int* __restrict__ mask, const float* __restrict__ rsum,
    const float* __restrict__ vox,
    const float* __restrict__ rW1, const float* __restrict__ rb1,
    const float* __restrict__ Wih, const float* __restrict__ Whh,
    const float* __restrict__ bih, const float* __restrict__ bhh,
    const float* __restrict__ rW2, const float* __restrict__ rb2,
    float* __restrict__ out)
{
    // k-major transposed W_hh for wave-uniform broadcast float4 reads
    __shared__ __align__(16) float sWt[RNNH][4 * RNNH];   // sWt[k][gu] = Whh[gu*20+k], 6.4 KB
    __shared__ __align__(16) float sA[4 * RNNH], sC[4 * RNNH];
    __shared__ float sW2r[RNNH];
    __shared__ float sb2o;
    int tid = threadIdx.x;
    for (int i = tid; i < 4 * RNNH * RNNH; i += blockDim.x) {
        int gu = i / RNNH, k = i % RNNH;
        sWt[k][gu] = Whh[i];
    }
    if (tid < 4 * RNNH) {
        float a = 0.0f, cc = bih[tid] + bhh[tid];
        for (int k = 0; k < RNNH; k++) {
            float w = Wih[tid * RNNH + k];
            a = fmaf(rW1[k], w, a);
            cc = fmaf(rb1[k], w, cc);
        }
        sA[tid] = a; sC[tid] = cc;
    }
    if (tid < RNNH) sW2r[tid] = rW2[tid];
    if (tid == 0) sb2o = rb2[0];
    __syncthreads();

    int row = blockIdx.x * blockDim.x + tid;
    if (row >= ROWS) return;

    float s = rsum[row];
    if (s == 0.0f) { out[row] = 0.0f; return; }

    unsigned int m = mask[row];
    int len = __popc(m);
    const float* vrow = vox + (size_t)row * M_EVC;

    float h[RNNH], c[RNNH];

    // ---- step 0 (h = c = 0): gates = x*A + C; f-gate term vanishes ----
    {
        float x0 = (m & 1u) ? vrow[0] : 0.0f;
#pragma unroll
        for (int u = 0; u < RNNH; u++) {
            float gi = fmaf(x0, sA[u],            sC[u]);
            float gg = fmaf(x0, sA[u + 2 * RNNH], sC[u + 2 * RNNH]);
            float go = fmaf(x0, sA[u + 3 * RNNH], sC[u + 3 * RNNH]);
            float cn = sigm(gi) * ftanh(gg);
            c[u] = cn;
            h[u] = sigm(go) * ftanh(cn);
        }
    }

    // ---- steps 1..len-1: full matvec, k-outer, 80 gate accumulators ----
    for (int j = 1; j < len; j++) {
        float xj = ((m >> j) & 1u) ? vrow[j] : 0.0f;
        float g[4 * RNNH];

        // init: g[gu] = C[gu] + xj * A[gu]   (uniform float4 LDS broadcasts)
#pragma unroll
        for (int q = 0; q < RNNH; q++) {   // 20 quads
            float4 a4 = ((const float4*)sA)[q];
            float4 c4 = ((const float4*)sC)[q];
            g[4 * q + 0] = fmaf(xj, a4.x, c4.x);
            g[4 * q + 1] = fmaf(xj, a4.y, c4.y);
            g[4 * q + 2] = fmaf(xj, a4.z, c4.z);
            g[4 * q + 3] = fmaf(xj, a4.w, c4.w);
        }

        // accumulate h @ Whh^T
#pragma unroll
        for (int k = 0; k < RNNH; k++) {
            float hk = h[k];
            const float4* wr = (const float4*)&sWt[k][0];   // wave-uniform
#pragma unroll
            for (int q = 0; q < RNNH; q++) {
                float4 w = wr[q];
                g[4 * q + 0] = fmaf(hk, w.x, g[4 * q + 0]);
                g[4 * q + 1] = fmaf(hk, w.y, g[4 * q + 1]);
                g[4 * q + 2] = fmaf(hk, w.z, g[4 * q + 2]);
                g[4 * q + 3] = fmaf(hk, w.w, g[4 * q + 3]);
            }
        }

        // epilogue: h updated in place (h is dead after the k-loop)
#pragma unroll
        for (int u = 0; u < RNNH; u++) {
            float cn = sigm(g[u + RNNH]) * c[u] + sigm(g[u]) * ftanh(g[u + 2 * RNNH]);
            c[u] = cn;
            h[u] = sigm(g[u + 3 * RNNH]) * ftanh(cn);
        }
    }

    float o = sb2o;
#pragma unroll
    for (int u = 0; u < RNNH; u++) o = fmaf(h[u], sW2r[u], o);
    out[row] = o;
}

extern "C" void kernel_launch(void* const* d_in, const int* in_sizes, int n_in,
                              void* d_out, int out_size, void* d_ws, size_t ws_size,
                              hipStream_t stream) {
    const float* ev     = (const float*)d_in[0];
    const float* mlp_W1 = (const float*)d_in[1];
    const float* mlp_b1 = (const float*)d_in[2];
    const float* mlp_W2 = (const float*)d_in[3];
    const float* mlp_b2 = (const float*)d_in[4];
    const float* mlp_W3 = (const float*)d_in[5];
    const float* mlp_b3 = (const float*)d_in[6];
    const float* rnn_W1 = (const float*)d_in[7];
    const float* rnn_b1 = (const float*)d_in[8];
    const float* W_ih   = (const float*)d_in[9];
    const float* W_hh   = (const float*)d_in[10];
    const float* b_ih   = (const float*)d_in[11];
    const float* b_hh   = (const float*)d_in[12];
    const float* rnn_W2 = (const float*)d_in[13];
    const float* rnn_b2 = (const float*)d_in[14];

    int n = in_sizes[0] / 7;
    float* outp = (float*)d_out;

    unsigned char* ws = (unsigned char*)d_ws;
    unsigned int* mask = (unsigned int*)ws;                    // ROWS u32
    float*        rsum = (float*)(ws + (size_t)ROWS * 4);      // ROWS f32
    float*        vox  = (float*)(ws + (size_t)ROWS * 8);      // ROWS*32 f32 (reads gated by mask)

    hipMemsetAsync(mask, 0, (size_t)ROWS * 8, stream);

    int blk = 256;
    int grid1 = (n + blk - 1) / blk;
    ev_mlp_scatter<<<grid1, blk, 0, stream>>>(ev, n, mlp_W1, mlp_b1, mlp_W2, mlp_b2,
                                              mlp_W3, mlp_b3, vox, mask, rsum);

    int grid2 = (ROWS + blk - 1) / blk;   // 4050
    row_lstm<<<grid2, blk, 0, stream>>>(mask, rsum, vox, rnn_W1, rnn_b1, W_ih, W_hh,
                                        b_ih, b_hh, rnn_W2, rnn_b2, outp);
}

// Round 3
// 3369.337 us; speedup vs baseline: 1.2155x; 1.2155x over previous
//
#include <hip/hip_runtime.h>
#include <math.h>

#define HH 180
#define WW 240
#define T_AGGC 3
#define NBC 4
#define BBC (NBC * T_AGGC)          // 12
#define M_EVC 32
#define ROWS (BBC * 2 * HH * WW)    // 1,036,800
#define MLPH 20
#define RNNH 20
#define LRELU_SLOPE 0.1f

__device__ __forceinline__ float lrelu(float x) { return x > 0.0f ? x : LRELU_SLOPE * x; }
__device__ __forceinline__ float sigm(float x)  { return 1.0f / (1.0f + __expf(-x)); }
__device__ __forceinline__ float ftanh(float x) { return 1.0f - 2.0f / (__expf(2.0f * x) + 1.0f); }

// ---------------- Kernel 1: per-event MLP + scatter ----------------
__global__ __launch_bounds__(256) void ev_mlp_scatter(
    const float* __restrict__ ev, int n,
    const float* __restrict__ W1, const float* __restrict__ b1,
    const float* __restrict__ W2, const float* __restrict__ b2,
    const float* __restrict__ W3, const float* __restrict__ b3,
    float* __restrict__ vox, unsigned int* __restrict__ mask,
    float* __restrict__ rsum)
{
    __shared__ __align__(16) float sW2[MLPH * MLPH];
    __shared__ float sW1[MLPH], sb1[MLPH], sb2[MLPH], sW3[MLPH];
    __shared__ float sb3;
    int tid = threadIdx.x;
    for (int i = tid; i < MLPH * MLPH; i += blockDim.x) sW2[i] = W2[i];
    if (tid < MLPH) { sW1[tid] = W1[tid]; sb1[tid] = b1[tid]; sb2[tid] = b2[tid]; sW3[tid] = W3[tid]; }
    if (tid == 0) sb3 = b3[0];
    __syncthreads();

    int i = blockIdx.x * blockDim.x + tid;
    if (i >= n) return;
    const float* e = ev + (size_t)i * 7;
    float t = e[3];

    float h1[MLPH];
#pragma unroll
    for (int k = 0; k < MLPH; k++) h1[k] = lrelu(fmaf(t, sW1[k], sb1[k]));

    float val = sb3;
#pragma unroll
    for (int j = 0; j < MLPH; j++) {
        float a = sb2[j];
        const float4* wr = (const float4*)&sW2[j * MLPH];
#pragma unroll
        for (int k4 = 0; k4 < MLPH / 4; k4++) {
            float4 w = wr[k4];
            a = fmaf(h1[k4 * 4 + 0], w.x, a);
            a = fmaf(h1[k4 * 4 + 1], w.y, a);
            a = fmaf(h1[k4 * 4 + 2], w.z, a);
            a = fmaf(h1[k4 * 4 + 3], w.w, a);
        }
        val = fmaf(lrelu(a), sW3[j], val);
    }

    int xi = (int)e[0], yi = (int)e[1], pi = (int)e[2];
    int ipi = (int)e[4], ti = (int)e[5], bi = (int)e[6];
    int row = xi + WW * yi + WW * HH * pi + 2 * WW * HH * (bi * T_AGGC + ti);
    int pos = ipi - 1;
    vox[(size_t)row * M_EVC + pos] = val;
    if (val != 0.0f) {                       // matches (vox != 0) semantics
        atomicOr(&mask[row], 1u << pos);
        atomicAdd(&rsum[row], val);
    }
}

// ---------------- Kernel 2: per-row LSTM (gate-accumulator layout) ----------------
// gates g[0:20]=i, g[20:40]=f, g[40:60]=g, g[60:80]=o
// NOTE: no min-waves hint — the 80-accumulator live set needs ~160-200 VGPRs;
// capping at 128 (round 2) spilled ~13 GB of scratch traffic.
__global__ __launch_bounds__(256) void row_lstm(
    const unsigned int* __restrict__ mask, const float* __restrict__ rsum,
    const float* __restrict__ vox,
    const float* __restrict__ rW1, const float* __restrict__ rb1,
    const float* __restrict__ Wih, const float* __restrict__ Whh,
    const float* __restrict__ bih, const float* __restrict__ bhh,
    const float* __restrict__ rW2, const float* __restrict__ rb2,
    float* __restrict__ out)
{
    // k-major transposed W_hh for wave-uniform broadcast float4 reads
    __shared__ __align__(16) float sWt[RNNH][4 * RNNH];   // sWt[k][gu] = Whh[gu*20+k], 6.4 KB
    __shared__ __align__(16) float sA[4 * RNNH], sC[4 * RNNH];
    __shared__ float sW2r[RNNH];
    __shared__ float sb2o;
    int tid = threadIdx.x;
    for (int i = tid; i < 4 * RNNH * RNNH; i += blockDim.x) {
        int gu = i / RNNH, k = i % RNNH;
        sWt[k][gu] = Whh[i];
    }
    if (tid < 4 * RNNH) {
        float a = 0.0f, cc = bih[tid] + bhh[tid];
        for (int k = 0; k < RNNH; k++) {
            float w = Wih[tid * RNNH + k];
            a = fmaf(rW1[k], w, a);
            cc = fmaf(rb1[k], w, cc);
        }
        sA[tid] = a; sC[tid] = cc;
    }
    if (tid < RNNH) sW2r[tid] = rW2[tid];
    if (tid == 0) sb2o = rb2[0];
    __syncthreads();

    int row = blockIdx.x * blockDim.x + tid;
    if (row >= ROWS) return;

    float s = rsum[row];
    if (s == 0.0f) { out[row] = 0.0f; return; }

    unsigned int m = mask[row];
    int len = __popc(m);
    const float* vrow = vox + (size_t)row * M_EVC;

    float h[RNNH], c[RNNH];

    // ---- step 0 (h = c = 0): gates = x*A + C; f-gate term vanishes ----
    {
        float x0 = (m & 1u) ? vrow[0] : 0.0f;
#pragma unroll
        for (int u = 0; u < RNNH; u++) {
            float gi = fmaf(x0, sA[u],            sC[u]);
            float gg = fmaf(x0, sA[u + 2 * RNNH], sC[u + 2 * RNNH]);
            float go = fmaf(x0, sA[u + 3 * RNNH], sC[u + 3 * RNNH]);
            float cn = sigm(gi) * ftanh(gg);
            c[u] = cn;
            h[u] = sigm(go) * ftanh(cn);
        }
    }

    // ---- steps 1..len-1: full matvec, k-outer, 80 gate accumulators ----
    for (int j = 1; j < len; j++) {
        float xj = ((m >> j) & 1u) ? vrow[j] : 0.0f;
        float g[4 * RNNH];

        // init: g[gu] = C[gu] + xj * A[gu]   (uniform float4 LDS broadcasts)
#pragma unroll
        for (int q = 0; q < RNNH; q++) {   // 20 quads
            float4 a4 = ((const float4*)sA)[q];
            float4 c4 = ((const float4*)sC)[q];
            g[4 * q + 0] = fmaf(xj, a4.x, c4.x);
            g[4 * q + 1] = fmaf(xj, a4.y, c4.y);
            g[4 * q + 2] = fmaf(xj, a4.z, c4.z);
            g[4 * q + 3] = fmaf(xj, a4.w, c4.w);
        }

        // accumulate h @ Whh^T
#pragma unroll
        for (int k = 0; k < RNNH; k++) {
            float hk = h[k];
            const float4* wr = (const float4*)&sWt[k][0];   // wave-uniform
#pragma unroll
            for (int q = 0; q < RNNH; q++) {
                float4 w = wr[q];
                g[4 * q + 0] = fmaf(hk, w.x, g[4 * q + 0]);
                g[4 * q + 1] = fmaf(hk, w.y, g[4 * q + 1]);
                g[4 * q + 2] = fmaf(hk, w.z, g[4 * q + 2]);
                g[4 * q + 3] = fmaf(hk, w.w, g[4 * q + 3]);
            }
        }

        // epilogue: h updated in place (h is dead after the k-loop)
#pragma unroll
        for (int u = 0; u < RNNH; u++) {
            float cn = sigm(g[u + RNNH]) * c[u] + sigm(g[u]) * ftanh(g[u + 2 * RNNH]);
            c[u] = cn;
            h[u] = sigm(g[u + 3 * RNNH]) * ftanh(cn);
        }
    }

    float o = sb2o;
#pragma unroll
    for (int u = 0; u < RNNH; u++) o = fmaf(h[u], sW2r[u], o);
    out[row] = o;
}

extern "C" void kernel_launch(void* const* d_in, const int* in_sizes, int n_in,
                              void* d_out, int out_size, void* d_ws, size_t ws_size,
                              hipStream_t stream) {
    const float* ev     = (const float*)d_in[0];
    const float* mlp_W1 = (const float*)d_in[1];
    const float* mlp_b1 = (const float*)d_in[2];
    const float* mlp_W2 = (const float*)d_in[3];
    const float* mlp_b2 = (const float*)d_in[4];
    const float* mlp_W3 = (const float*)d_in[5];
    const float* mlp_b3 = (const float*)d_in[6];
    const float* rnn_W1 = (const float*)d_in[7];
    const float* rnn_b1 = (const float*)d_in[8];
    const float* W_ih   = (const float*)d_in[9];
    const float* W_hh   = (const float*)d_in[10];
    const float* b_ih   = (const float*)d_in[11];
    const float* b_hh   = (const float*)d_in[12];
    const float* rnn_W2 = (const float*)d_in[13];
    const float* rnn_b2 = (const float*)d_in[14];

    int n = in_sizes[0] / 7;
    float* outp = (float*)d_out;

    unsigned char* ws = (unsigned char*)d_ws;
    unsigned int* mask = (unsigned int*)ws;                    // ROWS u32
    float*        rsum = (float*)(ws + (size_t)ROWS * 4);      // ROWS f32
    float*        vox  = (float*)(ws + (size_t)ROWS * 8);      // ROWS*32 f32 (reads gated by mask)

    hipMemsetAsync(mask, 0, (size_t)ROWS * 8, stream);

    int blk = 256;
    int grid1 = (n + blk - 1) / blk;
    ev_mlp_scatter<<<grid1, blk, 0, stream>>>(ev, n, mlp_W1, mlp_b1, mlp_W2, mlp_b2,
                                              mlp_W3, mlp_b3, vox, mask, rsum);

    int grid2 = (ROWS + blk - 1) / blk;   // 4050
    row_lstm<<<grid2, blk, 0, stream>>>(mask, rsum, vox, rnn_W1, rnn_b1, W_ih, W_hh,
                                        b_ih, b_hh, rnn_W2, rnn_b2, outp);
}

// Round 5
// 404.899 us; speedup vs baseline: 10.1146x; 8.3214x over previous
//
#include <hip/hip_runtime.h>
#include <math.h>

#define HH 180
#define WW 240
#define T_AGGC 3
#define NBC 4
#define BBC (NBC * T_AGGC)          // 12
#define M_EVC 32
#define ROWS (BBC * 2 * HH * WW)    // 1,036,800
#define MLPH 20
#define RNNH 20
#define LRELU_SLOPE 0.1f
#define HPAD 21                     // per-thread h stride in LDS (odd -> 2 lanes/bank, free)

__device__ __forceinline__ float lrelu(float x) { return x > 0.0f ? x : LRELU_SLOPE * x; }
__device__ __forceinline__ float sigm(float x)  { return 1.0f / (1.0f + __expf(-x)); }
__device__ __forceinline__ float ftanh(float x) { return 1.0f - 2.0f / (__expf(2.0f * x) + 1.0f); }

// ---------------- Kernel 1: per-event MLP + scatter ----------------
__global__ __launch_bounds__(256) void ev_mlp_scatter(
    const float* __restrict__ ev, int n,
    const float* __restrict__ W1, const float* __restrict__ b1,
    const float* __restrict__ W2, const float* __restrict__ b2,
    const float* __restrict__ W3, const float* __restrict__ b3,
    float* __restrict__ vox, unsigned int* __restrict__ mask,
    float* __restrict__ rsum)
{
    __shared__ __align__(16) float sW2[MLPH * MLPH];
    __shared__ float sW1[MLPH], sb1[MLPH], sb2[MLPH], sW3[MLPH];
    __shared__ float sb3;
    int tid = threadIdx.x;
    for (int i = tid; i < MLPH * MLPH; i += blockDim.x) sW2[i] = W2[i];
    if (tid < MLPH) { sW1[tid] = W1[tid]; sb1[tid] = b1[tid]; sb2[tid] = b2[tid]; sW3[tid] = W3[tid]; }
    if (tid == 0) sb3 = b3[0];
    __syncthreads();

    int i = blockIdx.x * blockDim.x + tid;
    if (i >= n) return;
    const float* e = ev + (size_t)i * 7;
    float t = e[3];

    float h1[MLPH];
#pragma unroll
    for (int k = 0; k < MLPH; k++) h1[k] = lrelu(fmaf(t, sW1[k], sb1[k]));

    float val = sb3;
#pragma unroll
    for (int j = 0; j < MLPH; j++) {
        float a = sb2[j];
        const float4* wr = (const float4*)&sW2[j * MLPH];
#pragma unroll
        for (int k4 = 0; k4 < MLPH / 4; k4++) {
            float4 w = wr[k4];
            a = fmaf(h1[k4 * 4 + 0], w.x, a);
            a = fmaf(h1[k4 * 4 + 1], w.y, a);
            a = fmaf(h1[k4 * 4 + 2], w.z, a);
            a = fmaf(h1[k4 * 4 + 3], w.w, a);
        }
        val = fmaf(lrelu(a), sW3[j], val);
    }

    int xi = (int)e[0], yi = (int)e[1], pi = (int)e[2];
    int ipi = (int)e[4], ti = (int)e[5], bi = (int)e[6];
    int row = xi + WW * yi + WW * HH * pi + 2 * WW * HH * (bi * T_AGGC + ti);
    int pos = ipi - 1;
    vox[(size_t)row * M_EVC + pos] = val;
    if (val != 0.0f) {                       // matches (vox != 0) semantics
        atomicOr(&mask[row], 1u << pos);
        atomicAdd(&rsum[row], val);
    }
}

// ---------------- Kernel 2: per-row LSTM ----------------
// Gate order in Wih/Whh/biases: i (0..19), f (20..39), g (40..59), o (60..79).
// Structure: h lives in per-thread padded LDS (so the k-reduction can be a real
// serial loop -> no runtime-indexed register arrays, no giant unrolled block).
// Each step = two 40-accumulator passes: pass1 (i,g) -> cand; pass2 (f,o) -> c,h.
__global__ __launch_bounds__(256) void row_lstm(
    const unsigned int* __restrict__ mask, const float* __restrict__ rsum,
    const float* __restrict__ vox,
    const float* __restrict__ rW1, const float* __restrict__ rb1,
    const float* __restrict__ Wih, const float* __restrict__ Whh,
    const float* __restrict__ bih, const float* __restrict__ bhh,
    const float* __restrict__ rW2, const float* __restrict__ rb2,
    float* __restrict__ out)
{
    __shared__ __align__(16) float sW1t[RNNH][2 * RNNH];  // [k][0..19]=i-gate row u at col k, [20..39]=g-gate
    __shared__ __align__(16) float sW2t[RNNH][2 * RNNH];  // [k][0..19]=f-gate, [20..39]=o-gate
    __shared__ __align__(16) float sA[4 * RNNH], sC[4 * RNNH];
    __shared__ float sW2r[RNNH];
    __shared__ float sb2o;
    __shared__ float sH[256 * HPAD];                      // per-thread h (21.5 KB)

    int tid = threadIdx.x;
    for (int i = tid; i < 4 * RNNH * RNNH; i += blockDim.x) {
        int gu = i / RNNH, k = i % RNNH;
        int gate = gu / RNNH, u = gu % RNNH;
        float w = Whh[i];
        if      (gate == 0) sW1t[k][u]        = w;   // i
        else if (gate == 2) sW1t[k][RNNH + u] = w;   // g
        else if (gate == 1) sW2t[k][u]        = w;   // f
        else                sW2t[k][RNNH + u] = w;   // o
    }
    if (tid < 4 * RNNH) {
        float a = 0.0f, cc = bih[tid] + bhh[tid];
        for (int k = 0; k < RNNH; k++) {
            float w = Wih[tid * RNNH + k];
            a = fmaf(rW1[k], w, a);
            cc = fmaf(rb1[k], w, cc);
        }
        sA[tid] = a; sC[tid] = cc;
    }
    if (tid < RNNH) sW2r[tid] = rW2[tid];
    if (tid == 0) sb2o = rb2[0];
    __syncthreads();

    int row = blockIdx.x * blockDim.x + tid;
    if (row >= ROWS) return;

    float s = rsum[row];
    if (s == 0.0f) { out[row] = 0.0f; return; }

    unsigned int m = mask[row];
    int len = __popc(m);
    const float* vrow = vox + (size_t)row * M_EVC;
    float* myh = &sH[tid * HPAD];

    float c[RNNH];
    float oacc;

    // ---- step 0 (h = c = 0): gates = x*A + C; f-gate term vanishes ----
    {
        float x0 = (m & 1u) ? vrow[0] : 0.0f;
        oacc = sb2o;
#pragma unroll
        for (int u = 0; u < RNNH; u++) {
            float gi = fmaf(x0, sA[u],            sC[u]);
            float gg = fmaf(x0, sA[u + 2 * RNNH], sC[u + 2 * RNNH]);
            float go = fmaf(x0, sA[u + 3 * RNNH], sC[u + 3 * RNNH]);
            float cn = sigm(gi) * ftanh(gg);
            c[u] = cn;
            float hu = sigm(go) * ftanh(cn);
            myh[u] = hu;
            oacc = fmaf(hu, sW2r[u], oacc);
        }
    }

    // ---- steps 1..len-1 ----
    for (int j = 1; j < len; j++) {
        float xj = ((m >> j) & 1u) ? vrow[j] : 0.0f;

        // ---- pass 1: i (accs 0..19) and g (accs 20..39) ----
        float a1[2 * RNNH];
#pragma unroll
        for (int q = 0; q < 5; q++) {
            float4 ai = ((const float4*)sA)[q],      ci = ((const float4*)sC)[q];       // i: quads 0..4
            float4 ag = ((const float4*)sA)[10 + q], cg = ((const float4*)sC)[10 + q];  // g: quads 10..14
            a1[4 * q + 0] = fmaf(xj, ai.x, ci.x);
            a1[4 * q + 1] = fmaf(xj, ai.y, ci.y);
            a1[4 * q + 2] = fmaf(xj, ai.z, ci.z);
            a1[4 * q + 3] = fmaf(xj, ai.w, ci.w);
            a1[RNNH + 4 * q + 0] = fmaf(xj, ag.x, cg.x);
            a1[RNNH + 4 * q + 1] = fmaf(xj, ag.y, cg.y);
            a1[RNNH + 4 * q + 2] = fmaf(xj, ag.z, cg.z);
            a1[RNNH + 4 * q + 3] = fmaf(xj, ag.w, cg.w);
        }
#pragma unroll 1
        for (int k = 0; k < RNNH; k++) {
            float hk = myh[k];
            const float4* wr = (const float4*)&sW1t[k][0];
#pragma unroll
            for (int q = 0; q < 10; q++) {
                float4 w = wr[q];
                a1[4 * q + 0] = fmaf(hk, w.x, a1[4 * q + 0]);
                a1[4 * q + 1] = fmaf(hk, w.y, a1[4 * q + 1]);
                a1[4 * q + 2] = fmaf(hk, w.z, a1[4 * q + 2]);
                a1[4 * q + 3] = fmaf(hk, w.w, a1[4 * q + 3]);
            }
        }
        float cand[RNNH];
#pragma unroll
        for (int u = 0; u < RNNH; u++) cand[u] = sigm(a1[u]) * ftanh(a1[RNNH + u]);

        // ---- pass 2: f (accs 0..19) and o (accs 20..39) ----
        float a2[2 * RNNH];
#pragma unroll
        for (int q = 0; q < 5; q++) {
            float4 af = ((const float4*)sA)[5 + q],  cf = ((const float4*)sC)[5 + q];   // f: quads 5..9
            float4 ao = ((const float4*)sA)[15 + q], co = ((const float4*)sC)[15 + q];  // o: quads 15..19
            a2[4 * q + 0] = fmaf(xj, af.x, cf.x);
            a2[4 * q + 1] = fmaf(xj, af.y, cf.y);
            a2[4 * q + 2] = fmaf(xj, af.z, cf.z);
            a2[4 * q + 3] = fmaf(xj, af.w, cf.w);
            a2[RNNH + 4 * q + 0] = fmaf(xj, ao.x, co.x);
            a2[RNNH + 4 * q + 1] = fmaf(xj, ao.y, co.y);
            a2[RNNH + 4 * q + 2] = fmaf(xj, ao.z, co.z);
            a2[RNNH + 4 * q + 3] = fmaf(xj, ao.w, co.w);
        }
#pragma unroll 1
        for (int k = 0; k < RNNH; k++) {
            float hk = myh[k];
            const float4* wr = (const float4*)&sW2t[k][0];
#pragma unroll
            for (int q = 0; q < 10; q++) {
                float4 w = wr[q];
                a2[4 * q + 0] = fmaf(hk, w.x, a2[4 * q + 0]);
                a2[4 * q + 1] = fmaf(hk, w.y, a2[4 * q + 1]);
                a2[4 * q + 2] = fmaf(hk, w.z, a2[4 * q + 2]);
                a2[4 * q + 3] = fmaf(hk, w.w, a2[4 * q + 3]);
            }
        }

        // ---- epilogue: c,h update + folded output dot-product ----
        oacc = sb2o;
#pragma unroll
        for (int u = 0; u < RNNH; u++) {
            float cn = fmaf(sigm(a2[u]), c[u], cand[u]);
            c[u] = cn;
            float hu = sigm(a2[RNNH + u]) * ftanh(cn);
            myh[u] = hu;
            oacc = fmaf(hu, sW2r[u], oacc);
        }
    }

    out[row] = oacc;
}

extern "C" void kernel_launch(void* const* d_in, const int* in_sizes, int n_in,
                              void* d_out, int out_size, void* d_ws, size_t ws_size,
                              hipStream_t stream) {
    const float* ev     = (const float*)d_in[0];
    const float* mlp_W1 = (const float*)d_in[1];
    const float* mlp_b1 = (const float*)d_in[2];
    const float* mlp_W2 = (const float*)d_in[3];
    const float* mlp_b2 = (const float*)d_in[4];
    const float* mlp_W3 = (const float*)d_in[5];
    const float* mlp_b3 = (const float*)d_in[6];
    const float* rnn_W1 = (const float*)d_in[7];
    const float* rnn_b1 = (const float*)d_in[8];
    const float* W_ih   = (const float*)d_in[9];
    const float* W_hh   = (const float*)d_in[10];
    const float* b_ih   = (const float*)d_in[11];
    const float* b_hh   = (const float*)d_in[12];
    const float* rnn_W2 = (const float*)d_in[13];
    const float* rnn_b2 = (const float*)d_in[14];

    int n = in_sizes[0] / 7;
    float* outp = (float*)d_out;

    unsigned char* ws = (unsigned char*)d_ws;
    unsigned int* mask = (unsigned int*)ws;                    // ROWS u32
    float*        rsum = (float*)(ws + (size_t)ROWS * 4);      // ROWS f32
    float*        vox  = (float*)(ws + (size_t)ROWS * 8);      // ROWS*32 f32 (reads gated by mask)

    hipMemsetAsync(mask, 0, (size_t)ROWS * 8, stream);

    int blk = 256;
    int grid1 = (n + blk - 1) / blk;
    ev_mlp_scatter<<<grid1, blk, 0, stream>>>(ev, n, mlp_W1, mlp_b1, mlp_W2, mlp_b2,
                                              mlp_W3, mlp_b3, vox, mask, rsum);

    int grid2 = (ROWS + blk - 1) / blk;   // 4050
    row_lstm<<<grid2, blk, 0, stream>>>(mask, rsum, vox, rnn_W1, rnn_b1, W_ih, W_hh,
                                        b_ih, b_hh, rnn_W2, rnn_b2, outp);
}